// Round 6
// baseline (340.322 us; speedup 1.0000x reference)
//
#include <hip/hip_runtime.h>
#include <stdint.h>

#define D_EMB 1024
#define NBATCH 8
#define SEQ 2048
#define MTOT (NBATCH*SEQ)   // 16384

typedef __attribute__((ext_vector_type(8))) short short8;
typedef __attribute__((ext_vector_type(16))) float f32x16;

__device__ __forceinline__ ushort bf16r(float x) {
  union { float f; uint32_t u; } c; c.f = x;
  return (ushort)((c.u + 0x7fffu + ((c.u >> 16) & 1u)) >> 16);
}

// async 16B/lane global->LDS (LDS dest must be wave-uniform base + lane*16)
__device__ __forceinline__ void cp16(const ushort* g, ushort* l) {
  __builtin_amdgcn_global_load_lds(
      (const __attribute__((address_space(1))) void*)g,
      (__attribute__((address_space(3))) void*)l, 16, 0, 0);
}

// merged: blocks <4096: wave-per-row cvt x->bf16 + vw[row]=x.wv_eff+sc[1]
//         blocks >=4096: cvt Wattn rows 0..2047 -> bf16 (q,k weights)
__global__ __launch_bounds__(256) void cvt_all(
    const float4* __restrict__ x4, const float4* __restrict__ W4,
    const float4* __restrict__ wv4, const float* __restrict__ sc,
    ushort* __restrict__ xb, ushort* __restrict__ wqkb, float* __restrict__ vw) {
  int tid = threadIdx.x;
  if (blockIdx.x < 4096) {
    int wave = tid >> 6, lane = tid & 63;
    long row = (long)blockIdx.x * 4 + wave;
    const float4* xr = x4 + row * 256;
    ushort* xo = xb + row * D_EMB;
    float s = 0.f;
    #pragma unroll
    for (int i = 0; i < 4; i++) {
      int idx = lane + i * 64;
      float4 v = xr[idx];
      float4 w = wv4[idx];
      *(ushort4*)(xo + idx * 4) = make_ushort4(bf16r(v.x), bf16r(v.y), bf16r(v.z), bf16r(v.w));
      s += v.x * w.x + v.y * w.y + v.z * w.z + v.w * w.w;
    }
    #pragma unroll
    for (int off = 32; off; off >>= 1) s += __shfl_xor(s, off);
    if (lane == 0) vw[row] = s + sc[1];
  } else {
    long base = (long)(blockIdx.x - 4096) * 1024 + tid;   // in float4 units
    #pragma unroll
    for (int i = 0; i < 4; i++) {
      long idx = base + i * 256;
      float4 v = W4[idx];
      *(ushort4*)(wqkb + idx * 4) = make_ushort4(bf16r(v.x), bf16r(v.y), bf16r(v.z), bf16r(v.w));
    }
  }
}

// init: b0 zero w_eff, b1 zero wv_eff, b2 sc[0]=bp.Wfc+bfc, b3..34 zero num/den (32768 f32)
__global__ void init_kernel(const float* __restrict__ bp, const float* __restrict__ Wfc,
                            const float* __restrict__ bfc,
                            float* __restrict__ w_eff, float* __restrict__ wv_eff,
                            float* __restrict__ numden, float* __restrict__ sc) {
  int tid = threadIdx.x;
  int b = blockIdx.x;
  if (b == 0) { w_eff[tid] = 0.f; return; }
  if (b == 1) { wv_eff[tid] = 0.f; return; }
  if (b >= 3) { numden[(long)(b - 3) * 1024 + tid] = 0.f; return; }
  float v = bp[tid] * Wfc[tid];
  int lane = tid & 63, w = tid >> 6;
  #pragma unroll
  for (int off = 32; off; off >>= 1) v += __shfl_xor(v, off);
  __shared__ float red[16];
  if (lane == 0) red[w] = v;
  __syncthreads();
  if (tid == 0) {
    float s = 0.f;
    #pragma unroll
    for (int i = 0; i < 16; i++) s += red[i];
    sc[0] = s + bfc[0];
  }
}

// w_eff[c] += sum over 16-d-chunk of Wfc[d]*Wp[d,c]   grid(4,64)
__global__ void prep1(const float* __restrict__ Wp, const float* __restrict__ Wfc,
                      float* __restrict__ w_eff) {
  int c = blockIdx.x * 256 + threadIdx.x;
  int d0 = blockIdx.y * 16;
  float s = 0.f;
  #pragma unroll
  for (int d = d0; d < d0 + 16; d++) s += Wfc[d] * Wp[(long)d * D_EMB + c];
  atomicAdd(&w_eff[c], s);
}

// grid(4,65): by<64 -> wv_eff[d] += sum over 16-c-chunk of w_eff[c]*Wattn[2048+c, d]
//             by==64 (bx==0) -> sc[1] = sum_c battn[2048+c]*w_eff[c]
__global__ void prep2(const float* __restrict__ Wattn, const float* __restrict__ battn,
                      const float* __restrict__ w_eff, float* __restrict__ wv_eff,
                      float* __restrict__ sc) {
  int tid = threadIdx.x;
  if (blockIdx.y == 64) {
    if (blockIdx.x != 0) return;
    float v = 0.f;
    #pragma unroll
    for (int i = 0; i < 4; i++) { int c = tid + i * 256; v += battn[2048 + c] * w_eff[c]; }
    int lane = tid & 63, w = tid >> 6;
    #pragma unroll
    for (int off = 32; off; off >>= 1) v += __shfl_xor(v, off);
    __shared__ float red[4];
    if (lane == 0) red[w] = v;
    __syncthreads();
    if (tid == 0) sc[1] = red[0] + red[1] + red[2] + red[3];
    return;
  }
  int d = blockIdx.x * 256 + tid;
  int c0 = blockIdx.y * 16;
  float s = 0.f;
  #pragma unroll
  for (int c = c0; c < c0 + 16; c++) s += w_eff[c] * Wattn[(long)(2048 + c) * D_EMB + d];
  atomicAdd(&wv_eff[d], s);
}

// ---------------- NT GEMM: 128x128 tile, BK=64, 32x32x16 bf16 MFMA ----------------
// FUSED=false (GEMM1, grid 16x128): C[m,n] = bf16(scale*acc + bias[n])
// FUSED=true  (GEMM2, grid 16x16x8): num[m] += sum_n exp(scale*acc)*vw[n], den[m] += sum_n exp
// XCD-aware remap: flat%8 = XCD (round-robin dispatch, m09).
//   GEMM1: XCD k owns M-rows [k*2048,(k+1)*2048) -> A exclusive per XCD-L2.
//   GEMM2: XCD k owns batch k -> 8 MB working set per XCD.
// LDS XOR swizzle f(row)=((row>>2)^row)&7 on 16B chunks: write dest = base+t*16
// (global_load_lds constraint), thread fetches global chunk kc=(t&7)^f(t>>3);
// read frag(row, 2*ks+h) at chunk (2*ks+h)^f(row) -> 2 lanes/bank-span = free.
template<bool FUSED>
__global__ __launch_bounds__(256, 4) void gemm_nt(
    const ushort* __restrict__ A, long lda, long sAz,
    const ushort* __restrict__ B, long ldb, long sBz,
    ushort* __restrict__ C, long ldc,
    const float* __restrict__ bias, float scale, int K,
    const float* __restrict__ vw, float* __restrict__ num, float* __restrict__ den) {
  __shared__ __align__(16) ushort lds_a[128 * 64];
  __shared__ __align__(16) ushort lds_b[128 * 64];

  // block remap for XCD/L2 locality
  long f = blockIdx.x + 16L * blockIdx.y + (FUSED ? 256L * blockIdx.z : 0L);
  int xcd = (int)(f & 7);
  long g = f >> 3;
  int bx = (int)(g & 15);
  int by, z;
  if (FUSED) { z = xcd; by = (int)(g >> 4); }
  else       { z = 0;   by = xcd * 16 + (int)(g >> 4); }

  const ushort* Az = A + (long)z * sAz;
  const ushort* Bz = B + (long)z * sBz;
  long m0 = (long)by * 128, n0 = (long)bx * 128;
  int t = threadIdx.x;
  int wave = t >> 6, lane = t & 63;
  int c = lane & 31, h = lane >> 5;
  int wm = (wave & 1) * 64, wn = (wave >> 1) * 64;

  f32x16 acc[2][2] = {};

  // staging: thread owns slots t, t+256, t+512, t+768 -> rows row0 + {0,32,64,96}
  int row0 = t >> 3;
  int kc = (t & 7) ^ (((row0 >> 2) ^ row0) & 7);
  const ushort* Ap = Az + (m0 + row0) * lda + kc * 8;
  const ushort* Bp = Bz + (n0 + row0) * ldb + kc * 8;
  long a32 = 32 * lda, b32 = 32 * ldb;

  int swz = ((c >> 2) ^ c) & 7;   // f(row) folds to this per-lane constant

  #pragma unroll 1
  for (int k0 = 0; k0 < K; k0 += 64) {
    if (k0) __syncthreads();
    cp16(Ap + k0,           lds_a + t * 8);
    cp16(Ap + k0 + a32,     lds_a + (t + 256) * 8);
    cp16(Ap + k0 + 2 * a32, lds_a + (t + 512) * 8);
    cp16(Ap + k0 + 3 * a32, lds_a + (t + 768) * 8);
    cp16(Bp + k0,           lds_b + t * 8);
    cp16(Bp + k0 + b32,     lds_b + (t + 256) * 8);
    cp16(Bp + k0 + 2 * b32, lds_b + (t + 512) * 8);
    cp16(Bp + k0 + 3 * b32, lds_b + (t + 768) * 8);
    __syncthreads();
    #pragma unroll
    for (int ks = 0; ks < 4; ks++) {
      int cidx = (2 * ks + h) ^ swz;
      short8 af[2], bf[2];
      #pragma unroll
      for (int i = 0; i < 2; i++)
        af[i] = *(const short8*)(lds_a + ((wm + i * 32 + c) * 8 + cidx) * 8);
      #pragma unroll
      for (int j = 0; j < 2; j++)
        bf[j] = *(const short8*)(lds_b + ((wn + j * 32 + c) * 8 + cidx) * 8);
      #pragma unroll
      for (int i = 0; i < 2; i++)
        #pragma unroll
        for (int j = 0; j < 2; j++)
          acc[i][j] = __builtin_amdgcn_mfma_f32_32x32x16_bf16(af[i], bf[j], acc[i][j], 0, 0, 0);
    }
  }

  // 32x32 C/D layout (verified m74/m101): col = c, row = (reg&3) + 8*(reg>>2) + 4*h
  if (!FUSED) {
    #pragma unroll
    for (int i = 0; i < 2; i++) {
      #pragma unroll
      for (int j = 0; j < 2; j++) {
        long col = n0 + wn + j * 32 + c;
        float bj = bias[col];
        #pragma unroll
        for (int reg = 0; reg < 16; reg++) {
          long row = m0 + wm + i * 32 + (reg & 3) + 8 * (reg >> 2) + 4 * h;
          C[row * ldc + col] = bf16r(acc[i][j][reg] * scale + bj);
        }
      }
    }
  } else {
    const float* vwz = vw + (long)z * SEQ + n0;
    float* numz = num + (long)z * SEQ + m0;
    float* denz = den + (long)z * SEQ + m0;
    float vwj[2];
    #pragma unroll
    for (int j = 0; j < 2; j++) vwj[j] = vwz[wn + j * 32 + c];
    #pragma unroll
    for (int i = 0; i < 2; i++) {
      #pragma unroll
      for (int reg = 0; reg < 16; reg++) {
        float sn = 0.f, sd = 0.f;
        #pragma unroll
        for (int j = 0; j < 2; j++) {
          float e = __expf(acc[i][j][reg] * scale);
          sd += e;
          sn += e * vwj[j];
        }
        #pragma unroll
        for (int off = 1; off < 32; off <<= 1) {   // reduce 32 cols within each half
          sn += __shfl_xor(sn, off);
          sd += __shfl_xor(sd, off);
        }
        if (c == 0) {   // lanes 0 (h=0) and 32 (h=1)
          int row = wm + i * 32 + (reg & 3) + 8 * (reg >> 2) + 4 * h;
          atomicAdd(&numz[row], sn);
          atomicAdd(&denz[row], sd);
        }
      }
    }
  }
}

// out[row] = num[row]/den[row] + c_eff
__global__ __launch_bounds__(256) void finalize(
    const float* __restrict__ num, const float* __restrict__ den,
    const float* __restrict__ sc, float* __restrict__ out) {
  long i = blockIdx.x * 256L + threadIdx.x;
  out[i] = num[i] / den[i] + sc[0];
}

extern "C" void kernel_launch(void* const* d_in, const int* in_sizes, int n_in,
                              void* d_out, int out_size, void* d_ws, size_t ws_size,
                              hipStream_t stream) {
  const float* x     = (const float*)d_in[0];
  const float* Wattn = (const float*)d_in[1];
  const float* battn = (const float*)d_in[2];
  const float* Wproj = (const float*)d_in[3];
  const float* bproj = (const float*)d_in[4];
  const float* Wfc   = (const float*)d_in[5];
  const float* bfc   = (const float*)d_in[6];
  float* out = (float*)d_out;

  // ws layout (bytes)
  const size_t OFF_XB    = 0;          // bf16 [16384][1024]  33554432
  const size_t OFF_WQKB  = 33554432;   // bf16 [2048][1024]    4194304
  const size_t OFF_QK    = 37748736;   // bf16 [16384][2048]  67108864
  const size_t OFF_NUM   = 104857600;  // f32  [16384]           65536
  const size_t OFF_DEN   = 104923136;  // f32  [16384]           65536
  const size_t OFF_VW    = 104988672;  // f32  [16384]           65536
  const size_t OFF_WEFF  = 105054208;  // f32  [1024]
  const size_t OFF_WVEFF = 105058304;  // f32  [1024]
  const size_t OFF_SC    = 105062400;  // f32  [2] {c_eff, vb_eff}
  const size_t NEED      = 105062408;
  if (ws_size < NEED) return;

  char* ws = (char*)d_ws;
  ushort* xb    = (ushort*)(ws + OFF_XB);
  ushort* wqkb  = (ushort*)(ws + OFF_WQKB);
  ushort* qk    = (ushort*)(ws + OFF_QK);
  float* num    = (float*)(ws + OFF_NUM);
  float* den    = (float*)(ws + OFF_DEN);
  float* vw     = (float*)(ws + OFF_VW);
  float* w_eff  = (float*)(ws + OFF_WEFF);
  float* wv_eff = (float*)(ws + OFF_WVEFF);
  float* sc     = (float*)(ws + OFF_SC);

  init_kernel<<<dim3(35), dim3(1024), 0, stream>>>(bproj, Wfc, bfc, w_eff, wv_eff, num, sc);
  prep1<<<dim3(4, 64), dim3(256), 0, stream>>>(Wproj, Wfc, w_eff);
  prep2<<<dim3(4, 65), dim3(256), 0, stream>>>(Wattn, battn, w_eff, wv_eff, sc);

  cvt_all<<<dim3(4096 + 512), dim3(256), 0, stream>>>(
      (const float4*)x, (const float4*)Wattn, (const float4*)wv_eff, sc, xb, wqkb, vw);

  // GEMM1: qk[m, n] = bf16( x[m,:] . Wattn[n,:] + battn[n] ), n in [0,2048)
  gemm_nt<false><<<dim3(16, 128, 1), dim3(256), 0, stream>>>(
      xb, (long)D_EMB, 0L, wqkb, (long)D_EMB, 0L,
      qk, 2048L, battn, 1.0f, D_EMB, nullptr, nullptr, nullptr);

  // GEMM2 fused: num/den partial softmax sums per row (scale = 1/sqrt(1024))
  gemm_nt<true><<<dim3(16, 16, NBATCH), dim3(256), 0, stream>>>(
      qk, 2048L, (long)SEQ * 2048, qk + 1024, 2048L, (long)SEQ * 2048,
      nullptr, 0L, nullptr, 0.03125f, D_EMB, vw, num, den);

  finalize<<<dim3(64), dim3(256), 0, stream>>>(num, den, sc, out);
}

// Round 7
// 269.557 us; speedup vs baseline: 1.2625x; 1.2625x over previous
//
#include <hip/hip_runtime.h>
#include <stdint.h>

#define D_EMB 1024
#define NBATCH 8
#define SEQ 2048
#define MTOT (NBATCH*SEQ)   // 16384

typedef __attribute__((ext_vector_type(8))) short short8;
typedef __attribute__((ext_vector_type(4))) float f32x4;

__device__ __forceinline__ ushort bf16r(float x) {
  union { float f; uint32_t u; } c; c.f = x;
  return (ushort)((c.u + 0x7fffu + ((c.u >> 16) & 1u)) >> 16);
}

// async 16B/lane global->LDS (LDS dest must be wave-uniform base + lane*16)
__device__ __forceinline__ void cp16(const ushort* g, ushort* l) {
  __builtin_amdgcn_global_load_lds(
      (const __attribute__((address_space(1))) void*)g,
      (__attribute__((address_space(3))) void*)l, 16, 0, 0);
}

// merged: blocks <4096: wave-per-row cvt x->bf16 + vw[row]=x.wv_eff+sc[1]
//         blocks >=4096: cvt Wattn rows 0..2047 -> bf16 (q,k weights)
__global__ __launch_bounds__(256) void cvt_all(
    const float4* __restrict__ x4, const float4* __restrict__ W4,
    const float4* __restrict__ wv4, const float* __restrict__ sc,
    ushort* __restrict__ xb, ushort* __restrict__ wqkb, float* __restrict__ vw) {
  int tid = threadIdx.x;
  if (blockIdx.x < 4096) {
    int wave = tid >> 6, lane = tid & 63;
    long row = (long)blockIdx.x * 4 + wave;
    const float4* xr = x4 + row * 256;
    ushort* xo = xb + row * D_EMB;
    float s = 0.f;
    #pragma unroll
    for (int i = 0; i < 4; i++) {
      int idx = lane + i * 64;
      float4 v = xr[idx];
      float4 w = wv4[idx];
      *(ushort4*)(xo + idx * 4) = make_ushort4(bf16r(v.x), bf16r(v.y), bf16r(v.z), bf16r(v.w));
      s += v.x * w.x + v.y * w.y + v.z * w.z + v.w * w.w;
    }
    #pragma unroll
    for (int off = 32; off; off >>= 1) s += __shfl_xor(s, off);
    if (lane == 0) vw[row] = s + sc[1];
  } else {
    long base = (long)(blockIdx.x - 4096) * 1024 + tid;   // in float4 units
    #pragma unroll
    for (int i = 0; i < 4; i++) {
      long idx = base + i * 256;
      float4 v = W4[idx];
      *(ushort4*)(wqkb + idx * 4) = make_ushort4(bf16r(v.x), bf16r(v.y), bf16r(v.z), bf16r(v.w));
    }
  }
}

// init: b0 zero w_eff, b1 zero wv_eff, b2 sc[0]=bp.Wfc+bfc, b3..34 zero num/den (32768 f32)
__global__ void init_kernel(const float* __restrict__ bp, const float* __restrict__ Wfc,
                            const float* __restrict__ bfc,
                            float* __restrict__ w_eff, float* __restrict__ wv_eff,
                            float* __restrict__ numden, float* __restrict__ sc) {
  int tid = threadIdx.x;
  int b = blockIdx.x;
  if (b == 0) { w_eff[tid] = 0.f; return; }
  if (b == 1) { wv_eff[tid] = 0.f; return; }
  if (b >= 3) { numden[(long)(b - 3) * 1024 + tid] = 0.f; return; }
  float v = bp[tid] * Wfc[tid];
  int lane = tid & 63, w = tid >> 6;
  #pragma unroll
  for (int off = 32; off; off >>= 1) v += __shfl_xor(v, off);
  __shared__ float red[16];
  if (lane == 0) red[w] = v;
  __syncthreads();
  if (tid == 0) {
    float s = 0.f;
    #pragma unroll
    for (int i = 0; i < 16; i++) s += red[i];
    sc[0] = s + bfc[0];
  }
}

// w_eff[c] += sum over 16-d-chunk of Wfc[d]*Wp[d,c]   grid(4,64)
__global__ void prep1(const float* __restrict__ Wp, const float* __restrict__ Wfc,
                      float* __restrict__ w_eff) {
  int c = blockIdx.x * 256 + threadIdx.x;
  int d0 = blockIdx.y * 16;
  float s = 0.f;
  #pragma unroll
  for (int d = d0; d < d0 + 16; d++) s += Wfc[d] * Wp[(long)d * D_EMB + c];
  atomicAdd(&w_eff[c], s);
}

// grid(4,65): by<64 -> wv_eff[d] += sum over 16-c-chunk of w_eff[c]*Wattn[2048+c, d]
//             by==64 (bx==0) -> sc[1] = sum_c battn[2048+c]*w_eff[c]
__global__ void prep2(const float* __restrict__ Wattn, const float* __restrict__ battn,
                      const float* __restrict__ w_eff, float* __restrict__ wv_eff,
                      float* __restrict__ sc) {
  int tid = threadIdx.x;
  if (blockIdx.y == 64) {
    if (blockIdx.x != 0) return;
    float v = 0.f;
    #pragma unroll
    for (int i = 0; i < 4; i++) { int c = tid + i * 256; v += battn[2048 + c] * w_eff[c]; }
    int lane = tid & 63, w = tid >> 6;
    #pragma unroll
    for (int off = 32; off; off >>= 1) v += __shfl_xor(v, off);
    __shared__ float red[4];
    if (lane == 0) red[w] = v;
    __syncthreads();
    if (tid == 0) sc[1] = red[0] + red[1] + red[2] + red[3];
    return;
  }
  int d = blockIdx.x * 256 + tid;
  int c0 = blockIdx.y * 16;
  float s = 0.f;
  #pragma unroll
  for (int c = c0; c < c0 + 16; c++) s += w_eff[c] * Wattn[(long)(2048 + c) * D_EMB + d];
  atomicAdd(&wv_eff[d], s);
}

// ---------------- NT GEMM: 128x128 tile, BK=64, 16x16x32 bf16 MFMA (R5 structure) ----------------
// FUSED=false: C[m,n] = bf16(scale*acc + bias[n])   (GEMM1 -> qk)
// FUSED=true : per-row partial softmax: num[m] += sum_n exp(scale*acc)*vw[n], den[m] += sum_n exp
// REMAP: XCD-aware block remap A/B test (flat%8 = XCD per m09 round-robin):
//   GEMM1 (REMAP=true): XCD k owns M-rows [k*2048,(k+1)*2048) -> A panel exclusive per XCD-L2.
//   GEMM2 (REMAP=false): identity mapping — within-run control.
// LDS: [128 rows][8 chunks of 16B], XOR swizzle chunk_stored = chunk ^ (row&7)  (R5, 0 conflicts)
template<bool FUSED, bool REMAP>
__global__ __launch_bounds__(256, 4) void gemm_nt(
    const ushort* __restrict__ A, long lda, long sAz,
    const ushort* __restrict__ B, long ldb, long sBz,
    ushort* __restrict__ C, long ldc,
    const float* __restrict__ bias, float scale, int K,
    const float* __restrict__ vw, float* __restrict__ num, float* __restrict__ den) {
  __shared__ __align__(16) ushort lds_a[128 * 64];
  __shared__ __align__(16) ushort lds_b[128 * 64];

  int bx, by, z;
  if (REMAP) {
    long f = blockIdx.x + 16L * blockIdx.y + (FUSED ? 256L * blockIdx.z : 0L);
    int xcd = (int)(f & 7);
    long g = f >> 3;
    bx = (int)(g & 15);
    if (FUSED) { z = xcd; by = (int)(g >> 4); }
    else       { z = 0;   by = xcd * 16 + (int)(g >> 4); }
  } else {
    bx = blockIdx.x; by = blockIdx.y; z = blockIdx.z;
  }

  const ushort* Az = A + (long)z * sAz;
  const ushort* Bz = B + (long)z * sBz;
  long m0 = (long)by * 128, n0 = (long)bx * 128;
  int t = threadIdx.x;
  int wave = t >> 6, lane = t & 63;
  int r = lane & 15, q = lane >> 4;
  int wm = (wave & 1) * 64, wn = (wave >> 1) * 64;

  f32x4 acc[4][4] = {};

  // staging: thread owns slots t, t+256, t+512, t+768 -> rows row0 + {0,32,64,96}
  int row0 = t >> 3;
  int kc = (t & 7) ^ (row0 & 7);
  const ushort* Ap = Az + (m0 + row0) * lda + kc * 8;
  const ushort* Bp = Bz + (n0 + row0) * ldb + kc * 8;
  long a32 = 32 * lda, b32 = 32 * ldb;

  int swz = r & 7;

  #pragma unroll 1
  for (int k0 = 0; k0 < K; k0 += 64) {
    if (k0) __syncthreads();
    cp16(Ap + k0,            lds_a + t * 8);
    cp16(Ap + k0 + a32,      lds_a + (t + 256) * 8);
    cp16(Ap + k0 + 2 * a32,  lds_a + (t + 512) * 8);
    cp16(Ap + k0 + 3 * a32,  lds_a + (t + 768) * 8);
    cp16(Bp + k0,            lds_b + t * 8);
    cp16(Bp + k0 + b32,      lds_b + (t + 256) * 8);
    cp16(Bp + k0 + 2 * b32,  lds_b + (t + 512) * 8);
    cp16(Bp + k0 + 3 * b32,  lds_b + (t + 768) * 8);
    __syncthreads();
    #pragma unroll
    for (int kk = 0; kk < 2; kk++) {
      int cidx = (kk * 4 + q) ^ swz;
      short8 af[4], bf[4];
      #pragma unroll
      for (int i = 0; i < 4; i++)
        af[i] = *(const short8*)(lds_a + ((wm + i * 16 + r) * 8 + cidx) * 8);
      #pragma unroll
      for (int j = 0; j < 4; j++)
        bf[j] = *(const short8*)(lds_b + ((wn + j * 16 + r) * 8 + cidx) * 8);
      #pragma unroll
      for (int i = 0; i < 4; i++)
        #pragma unroll
        for (int j = 0; j < 4; j++)
          acc[i][j] = __builtin_amdgcn_mfma_f32_16x16x32_bf16(af[i], bf[j], acc[i][j], 0, 0, 0);
    }
  }

  // C/D layout (verified): row = wm+i*16+q*4+rr, col = wn+j*16+r
  if (!FUSED) {
    #pragma unroll
    for (int i = 0; i < 4; i++) {
      #pragma unroll
      for (int j = 0; j < 4; j++) {
        long col = n0 + wn + j * 16 + r;
        float bj = bias[col];
        #pragma unroll
        for (int rr = 0; rr < 4; rr++) {
          long row = m0 + wm + i * 16 + q * 4 + rr;
          C[row * ldc + col] = bf16r(acc[i][j][rr] * scale + bj);
        }
      }
    }
  } else {
    const float* vwz = vw + (long)z * SEQ + n0;
    float* numz = num + (long)z * SEQ + m0;
    float* denz = den + (long)z * SEQ + m0;
    float vwj[4];
    #pragma unroll
    for (int j = 0; j < 4; j++) vwj[j] = vwz[wn + j * 16 + r];
    #pragma unroll
    for (int i = 0; i < 4; i++) {
      #pragma unroll
      for (int rr = 0; rr < 4; rr++) {
        float sn = 0.f, sd = 0.f;
        #pragma unroll
        for (int j = 0; j < 4; j++) {
          float e = __expf(acc[i][j][rr] * scale);
          sd += e;
          sn += e * vwj[j];
        }
        #pragma unroll
        for (int off = 1; off < 16; off <<= 1) {
          sn += __shfl_xor(sn, off);
          sd += __shfl_xor(sd, off);
        }
        if (r == 0) {
          int row = wm + i * 16 + q * 4 + rr;
          atomicAdd(&numz[row], sn);
          atomicAdd(&denz[row], sd);
        }
      }
    }
  }
}

// out[row] = num[row]/den[row] + c_eff
__global__ __launch_bounds__(256) void finalize(
    const float* __restrict__ num, const float* __restrict__ den,
    const float* __restrict__ sc, float* __restrict__ out) {
  long i = blockIdx.x * 256L + threadIdx.x;
  out[i] = num[i] / den[i] + sc[0];
}

extern "C" void kernel_launch(void* const* d_in, const int* in_sizes, int n_in,
                              void* d_out, int out_size, void* d_ws, size_t ws_size,
                              hipStream_t stream) {
  const float* x     = (const float*)d_in[0];
  const float* Wattn = (const float*)d_in[1];
  const float* battn = (const float*)d_in[2];
  const float* Wproj = (const float*)d_in[3];
  const float* bproj = (const float*)d_in[4];
  const float* Wfc   = (const float*)d_in[5];
  const float* bfc   = (const float*)d_in[6];
  float* out = (float*)d_out;

  // ws layout (bytes)
  const size_t OFF_XB    = 0;          // bf16 [16384][1024]  33554432
  const size_t OFF_WQKB  = 33554432;   // bf16 [2048][1024]    4194304
  const size_t OFF_QK    = 37748736;   // bf16 [16384][2048]  67108864
  const size_t OFF_NUM   = 104857600;  // f32  [16384]           65536
  const size_t OFF_DEN   = 104923136;  // f32  [16384]           65536
  const size_t OFF_VW    = 104988672;  // f32  [16384]           65536
  const size_t OFF_WEFF  = 105054208;  // f32  [1024]
  const size_t OFF_WVEFF = 105058304;  // f32  [1024]
  const size_t OFF_SC    = 105062400;  // f32  [2] {c_eff, vb_eff}
  const size_t NEED      = 105062408;
  if (ws_size < NEED) return;

  char* ws = (char*)d_ws;
  ushort* xb    = (ushort*)(ws + OFF_XB);
  ushort* wqkb  = (ushort*)(ws + OFF_WQKB);
  ushort* qk    = (ushort*)(ws + OFF_QK);
  float* num    = (float*)(ws + OFF_NUM);
  float* den    = (float*)(ws + OFF_DEN);
  float* vw     = (float*)(ws + OFF_VW);
  float* w_eff  = (float*)(ws + OFF_WEFF);
  float* wv_eff = (float*)(ws + OFF_WVEFF);
  float* sc     = (float*)(ws + OFF_SC);

  init_kernel<<<dim3(35), dim3(1024), 0, stream>>>(bproj, Wfc, bfc, w_eff, wv_eff, num, sc);
  prep1<<<dim3(4, 64), dim3(256), 0, stream>>>(Wproj, Wfc, w_eff);
  prep2<<<dim3(4, 65), dim3(256), 0, stream>>>(Wattn, battn, w_eff, wv_eff, sc);

  cvt_all<<<dim3(4096 + 512), dim3(256), 0, stream>>>(
      (const float4*)x, (const float4*)Wattn, (const float4*)wv_eff, sc, xb, wqkb, vw);

  // GEMM1 (REMAP=true): qk[m, n] = bf16( x[m,:] . Wattn[n,:] + battn[n] ), n in [0,2048)
  gemm_nt<false, true><<<dim3(16, 128, 1), dim3(256), 0, stream>>>(
      xb, (long)D_EMB, 0L, wqkb, (long)D_EMB, 0L,
      qk, 2048L, battn, 1.0f, D_EMB, nullptr, nullptr, nullptr);

  // GEMM2 (REMAP=false, control): fused num/den partial softmax sums (scale = 1/sqrt(1024))
  gemm_nt<true, false><<<dim3(16, 16, NBATCH), dim3(256), 0, stream>>>(
      qk, 2048L, (long)SEQ * 2048, qk + 1024, 2048L, (long)SEQ * 2048,
      nullptr, 0L, nullptr, 0.03125f, D_EMB, vw, num, den);

  finalize<<<dim3(64), dim3(256), 0, stream>>>(num, den, sc, out);
}